// Round 9
// baseline (181.305 us; speedup 1.0000x reference)
//
#include <hip/hip_runtime.h>
#include <cstdint>

#define NB 2
#define NSEQ 2048
#define CDIM 768
#define NH 12
#define HD 64
#define NTOK (NB*NSEQ)        // 4096
#define QKV_COLS (3*CDIM)     // 2304
#define NBLK ((NSEQ/64)*NH*NB) // 768 attn blocks

typedef short bf16x8 __attribute__((ext_vector_type(8)));   // 8 bf16 = 4 VGPR
typedef short bf16x4 __attribute__((ext_vector_type(4)));
typedef float f32x4  __attribute__((ext_vector_type(4)));
typedef short short4v __attribute__((ext_vector_type(4)));
typedef unsigned int uint2v __attribute__((ext_vector_type(2)));
typedef unsigned int uint4v __attribute__((ext_vector_type(4)));

#define MFMA16(a,b,c) __builtin_amdgcn_mfma_f32_16x16x32_bf16(a,b,c,0,0,0)

__device__ __forceinline__ short f2b(float f) {
    uint32_t u = __builtin_bit_cast(uint32_t, f);
    u += 0x7fffu + ((u >> 16) & 1u);
    return (short)(u >> 16);
}
__device__ __forceinline__ unsigned pack2(float a, float b) {
    unsigned ua = __builtin_bit_cast(unsigned, a) + 0x7fffu;
    unsigned ub = __builtin_bit_cast(unsigned, b) + 0x7fffu;
    return __builtin_amdgcn_perm(ub, ua, 0x07060302u);
}
__device__ __forceinline__ void gll16(const short* g, short* l) {
    __builtin_amdgcn_global_load_lds(
        (const __attribute__((address_space(1))) unsigned int*)g,
        (__attribute__((address_space(3))) unsigned int*)l, 16, 0, 0);
}

// ---------------------------------------------------------------------------
// Merged prep: x fp32->bf16 (blocks 0..3071), w_qkv T (..4799), w_proj T (..5375)
// ---------------------------------------------------------------------------
__global__ __launch_bounds__(256) void prep_kernel(
    const float* __restrict__ x, const float* __restrict__ w_qkv,
    const float* __restrict__ w_proj,
    short* __restrict__ xb, short* __restrict__ wqt, short* __restrict__ wpt)
{
    __shared__ float tile[32][33];
    const int bid = blockIdx.x, t = threadIdx.x;
    if (bid < 3072) {
        int i = bid * 256 + t;
        float4 v = ((const float4*)x)[i];
        short4v o = { f2b(v.x), f2b(v.y), f2b(v.z), f2b(v.w) };
        ((short4v*)xb)[i] = o;
        return;
    }
    const float* w; short* wt; int K, NC, n0, k0;
    if (bid < 3072 + 1728) {
        int r = bid - 3072;
        w = w_qkv; wt = wqt; K = CDIM; NC = QKV_COLS;
        n0 = (r % 72) * 32; k0 = (r / 72) * 32;
    } else {
        int r = bid - 4800;
        w = w_proj; wt = wpt; K = CDIM; NC = CDIM;
        n0 = (r % 24) * 32; k0 = (r / 24) * 32;
    }
    #pragma unroll
    for (int i = 0; i < 4; ++i) {
        int idx = t + i * 256; int r = idx >> 5, c = idx & 31;
        tile[r][c] = w[(size_t)(k0 + r) * NC + n0 + c];
    }
    __syncthreads();
    #pragma unroll
    for (int i = 0; i < 4; ++i) {
        int idx = t + i * 256; int r = idx >> 5, c = idx & 31;
        wt[(size_t)(n0 + r) * K + k0 + c] = f2b(tile[c][r]);
    }
}

// ---------------------------------------------------------------------------
// Shared GEMM pieces: double-buffered BK=32, ONE barrier per stage.
// ---------------------------------------------------------------------------
#define STAGEG(K0, B) do {                                                       \
    short* a_ = As + (B)*4096; short* b_ = Bs + (B)*4096;                        \
    gll16(ag0 + (K0), a_ + wid*512);                                             \
    gll16(ag1 + (K0), a_ + 2048 + wid*512);                                      \
    gll16(bg0 + (K0), b_ + wid*512);                                             \
    gll16(bg1 + (K0), b_ + 2048 + wid*512);                                      \
} while (0)

#define COMPUTEG(B) do {                                                         \
    const short* A_ = As + (B)*4096; const short* B_ = Bs + (B)*4096;            \
    bf16x8 af_[4], bf_[4];                                                       \
    _Pragma("unroll")                                                            \
    for (int i = 0; i < 4; ++i)                                                  \
        af_[i] = *(const bf16x8*)&A_[(wA*64 + i*16 + l16) * 32 + quad*8];        \
    _Pragma("unroll")                                                            \
    for (int j = 0; j < 4; ++j)                                                  \
        bf_[j] = *(const bf16x8*)&B_[(wB*64 + j*16 + l16) * 32 + quad*8];        \
    _Pragma("unroll")                                                            \
    for (int i = 0; i < 4; ++i)                                                  \
        _Pragma("unroll")                                                        \
        for (int j = 0; j < 4; ++j)                                              \
            acc[i][j] = MFMA16(af_[i], bf_[j], acc[i][j]);                       \
} while (0)

#define GEMM_LOOP() do {                                                         \
    STAGEG(0, 0); __syncthreads();                                               \
    for (int k0 = 0; k0 < CDIM; k0 += 64) {                                      \
        STAGEG(k0 + 32, 1);                                                      \
        COMPUTEG(0);                                                             \
        __syncthreads();                                                         \
        STAGEG((k0 + 64 < CDIM) ? k0 + 64 : 0, 0);                               \
        COMPUTEG(1);                                                             \
        __syncthreads();                                                         \
    }                                                                            \
} while (0)

// ---------------------------------------------------------------------------
// GEMM1: qkv. Epilogue: q pre-scaled by 0.125.
// ---------------------------------------------------------------------------
__global__ __launch_bounds__(256) void gemm_qkv(
    const short* __restrict__ A /*wqt[2304][768]*/,
    const short* __restrict__ B /*xb [4096][768]*/,
    short* __restrict__ qb, short* __restrict__ kb, short* __restrict__ vt)
{
    __shared__ short As[8192];
    __shared__ short Bs[8192];
    const int t = threadIdx.x;
    const int lane = t & 63, wid = t >> 6;
    const int quad = lane >> 4, l16 = lane & 15;
    const int wA = wid >> 1, wB = wid & 1;
    const int n0 = blockIdx.x * 128;
    const int m0 = blockIdx.y * 128;

    const int srow = wid * 16 + (lane >> 2), schunk = (lane & 3) * 8;
    const short* ag0 = A + (size_t)(n0 + srow) * CDIM + schunk;
    const short* ag1 = ag0 + (size_t)64 * CDIM;
    const short* bg0 = B + (size_t)(m0 + srow) * CDIM + schunk;
    const short* bg1 = bg0 + (size_t)64 * CDIM;

    f32x4 acc[4][4] = {};
    GEMM_LOOP();

    const int colbase = n0 + wA * 64;
    const int s = colbase / CDIM;
    const int h = (colbase - s * CDIM) >> 6;
    const int b = m0 >> 11;
    const size_t bh = (size_t)(b * NH + h);
    const float qsc = (s == 0) ? 0.125f : 1.0f;
    #pragma unroll
    for (int i = 0; i < 4; ++i) {
        const int d0 = i*16 + quad*4;
        #pragma unroll
        for (int j = 0; j < 4; ++j) {
            int tok = (m0 + wB*64 + j*16 + l16) & (NSEQ - 1);
            if (s < 2) {
                short* dst = (s == 0 ? qb : kb) + (bh * NSEQ + tok) * HD + d0;
                short4v o = { f2b(acc[i][j][0] * qsc), f2b(acc[i][j][1] * qsc),
                              f2b(acc[i][j][2] * qsc), f2b(acc[i][j][3] * qsc) };
                *(short4v*)dst = o;
            } else {
                short* dst = vt + (bh * HD + d0) * NSEQ + tok;
                #pragma unroll
                for (int r = 0; r < 4; ++r)
                    dst[(size_t)r * NSEQ] = f2b(acc[i][j][r]);
            }
        }
    }
}

// ---------------------------------------------------------------------------
// Flash attention v9: 64-key tiles, dbuf LDS (2 x (K 8KB + V 8KB) = 32 KB),
// 1 barrier/tile. PV fires every 2nd tile (128-key pairing): even tile holds
// its P-halves (packed) and V-halves in 16 VGPRs, odd tile completes the
// 8-key operands and issues the 16 PV MFMAs. Swizzled staging, conflict-free.
// ---------------------------------------------------------------------------
#define STAGE64(KT, BUF) do {                                                    \
    short* kd_ = (BUF);                                                          \
    short* vd_ = (BUF) + 4096;                                                   \
    _Pragma("unroll")                                                            \
    for (int j = 0; j < 2; ++j) {                                                \
        gll16(kp + (size_t)((KT) + sRow[j]) * HD + sC[j]*8, kd_ + wid*1024 + j*512); \
        gll16(vp + (size_t)sRow[j] * NSEQ + (KT) + sC[j]*8, vd_ + wid*1024 + j*512); \
    }                                                                            \
} while (0)

// S + exp for one 64-key tile; outputs pP (packed 4 keys/jt) and vL (V 4 keys/it)
#define BODY_S(KT, BUF, pP, vL) do {                                             \
    const short* Kb_ = (BUF);                                                    \
    const short* Vb_ = (BUF) + 4096;                                             \
    int4 mi_ = *(const int4*)(mp + (KT) + kbase);                                \
    bf16x8 kf0_ = *(const bf16x8*)&Kb_[krow64 + kc0];                            \
    bf16x8 kf1_ = *(const bf16x8*)&Kb_[krow64 + kc1];                            \
    f32x4 s_[4] = {};                                                            \
    _Pragma("unroll")                                                            \
    for (int jt = 0; jt < 4; ++jt) {                                             \
        s_[jt] = MFMA16(kf0_, qf[jt][0], s_[jt]);                                \
        s_[jt] = MFMA16(kf1_, qf[jt][1], s_[jt]);                                \
    }                                                                            \
    float4 m_ = {(float)mi_.x, (float)mi_.y, (float)mi_.z, (float)mi_.w};        \
    _Pragma("unroll")                                                            \
    for (int jt = 0; jt < 4; ++jt) {                                             \
        float e0 = __expf(s_[jt][0]) * m_.x;                                     \
        float e1 = __expf(s_[jt][1]) * m_.y;                                     \
        float e2 = __expf(s_[jt][2]) * m_.z;                                     \
        float e3 = __expf(s_[jt][3]) * m_.w;                                     \
        l[jt] += (e0 + e1) + (e2 + e3);                                          \
        pP[jt] = (uint2v){ pack2(e0, e1), pack2(e2, e3) };                       \
    }                                                                            \
    _Pragma("unroll")                                                            \
    for (int it = 0; it < 4; ++it)                                               \
        vL[it] = *(const bf16x4*)&Vb_[(it*16 + l16)*64 + vslot + vsub];          \
} while (0)

#define BODY_PV(pLo, vLo, pHi, vHi) do {                                         \
    bf16x8 pb_[4];                                                               \
    _Pragma("unroll")                                                            \
    for (int jt = 0; jt < 4; ++jt) {                                             \
        uint4v u_ = { pLo[jt].x, pLo[jt].y, pHi[jt].x, pHi[jt].y };              \
        pb_[jt] = __builtin_bit_cast(bf16x8, u_);                                \
    }                                                                            \
    _Pragma("unroll")                                                            \
    for (int it = 0; it < 4; ++it) {                                             \
        bf16x8 vf_ = __builtin_shufflevector(vLo[it], vHi[it], 0,1,2,3,4,5,6,7); \
        _Pragma("unroll")                                                        \
        for (int jt = 0; jt < 4; ++jt)                                           \
            o_acc[it][jt] = MFMA16(vf_, pb_[jt], o_acc[it][jt]);                 \
    }                                                                            \
} while (0)

__global__ __launch_bounds__(256) void attn_kernel(
    const short* __restrict__ qb, const short* __restrict__ kb,
    const short* __restrict__ vt, const int* __restrict__ mask,
    short* __restrict__ ao)
{
    __shared__ __align__(16) short KV2[2][8192];   // [buf][K 8KB | V 8KB]
    float (*Ob)[68] = (float(*)[68])KV2;           // epilogue alias (17.4 KB)
    float (*lsum)[64] = (float(*)[64])((char*)KV2 + 17408);

    const int t = threadIdx.x;
    const int lane = t & 63, wid = t >> 6;
    const int quad = lane >> 4, l16 = lane & 15;
    // XCD swizzle: XCD = id%8 owns bh in {xcd, xcd+8, xcd+16}
    const int id = blockIdx.x;
    const int idx = id >> 3;
    const int bh = (id & 7) + ((idx % 3) << 3);
    const int q0 = (idx / 3) << 6;
    const int b = bh / NH, h = bh - b * NH;
    const size_t hoff = (size_t)bh * NSEQ * HD;
    const short* qp = qb + hoff;     // [N][64]  (q pre-scaled by 0.125)
    const short* kp = kb + hoff;     // [N][64]
    const short* vp = vt + hoff;     // [64][N]
    const int* mp = mask + b * NSEQ;
    const int kbase = wid * 16 + quad * 4;

    // staging decode: K and V tiles are both 64 rows x 128 B
    int sRow[2], sC[2];
    #pragma unroll
    for (int j = 0; j < 2; ++j) {
        sRow[j] = wid * 16 + j * 8 + (lane >> 3);
        sC[j]   = (lane & 7) ^ (sRow[j] & 7);
    }
    // read-side swizzle constants
    const int r7 = l16 & 7;
    const int krow64 = (wid * 16 + l16) * 64;
    const int kc0 = ((quad       ^ r7) << 3);
    const int kc1 = (((quad + 4) ^ r7) << 3);
    const int vslot = (((wid*2 + (quad >> 1)) ^ r7) << 3);
    const int vsub  = (quad & 1) * 4;

    // Q fragments (B-operand, all 64 queries), loop-invariant
    bf16x8 qf[4][2];
    #pragma unroll
    for (int jt = 0; jt < 4; ++jt) {
        const short* qr = qp + (size_t)(q0 + jt*16 + l16) * HD + quad*8;
        qf[jt][0] = *(const bf16x8*)qr;
        qf[jt][1] = *(const bf16x8*)(qr + 32);
    }

    f32x4 o_acc[4][4] = {};
    float l[4] = {0.f, 0.f, 0.f, 0.f};
    uint2v pLo[4], pHi[4];
    bf16x4 vLo[4], vHi[4];

    STAGE64(0, KV2[0]);
    __syncthreads();

    for (int kt = 0; kt < NSEQ; kt += 128) {
        STAGE64(kt + 64, KV2[1]);
        BODY_S(kt, KV2[0], pLo, vLo);            // even tile: S/exp, hold halves
        __syncthreads();
        STAGE64((kt + 128) & (NSEQ - 1), KV2[0]);
        BODY_S(kt + 64, KV2[1], pHi, vHi);       // odd tile
        BODY_PV(pLo, vLo, pHi, vHi);             // 16 PV MFMAs per 128 keys
        __syncthreads();
    }

    // ---- epilogue (smem re-aliased; last barrier already passed) ----
    #pragma unroll
    for (int jt = 0; jt < 4; ++jt) {
        l[jt] += __shfl_xor(l[jt], 16);
        l[jt] += __shfl_xor(l[jt], 32);
        if (quad == 0) lsum[wid][jt*16 + l16] = l[jt];
    }
    for (int w = 0; w < 4; ++w) {
        __syncthreads();
        if (wid == w) {
            #pragma unroll
            for (int it = 0; it < 4; ++it)
                #pragma unroll
                for (int jt = 0; jt < 4; ++jt)
                    #pragma unroll
                    for (int r = 0; r < 4; ++r) {
                        if (w == 0)
                            Ob[it*16 + quad*4 + r][jt*16 + l16] = o_acc[it][jt][r];
                        else
                            Ob[it*16 + quad*4 + r][jt*16 + l16] += o_acc[it][jt][r];
                    }
        }
    }
    __syncthreads();

    {
        const int ql = t >> 2, dc = (t & 3) * 16;
        float inv = 1.0f / (((lsum[0][ql] + lsum[1][ql]) +
                             (lsum[2][ql] + lsum[3][ql])));
        bf16x8 o8a, o8b;
        #pragma unroll
        for (int d = 0; d < 8; ++d) o8a[d] = f2b(Ob[dc + d][ql] * inv);
        #pragma unroll
        for (int d = 0; d < 8; ++d) o8b[d] = f2b(Ob[dc + 8 + d][ql] * inv);
        int tok = b * NSEQ + q0 + ql;
        short* dst = ao + (size_t)tok * CDIM + h * HD + dc;
        *(bf16x8*)dst = o8a;
        *(bf16x8*)(dst + 8) = o8b;
    }
}

// ---------------------------------------------------------------------------
// GEMM2: out = ao @ w_proj + bias (fp32), dbuf K-loop.
// ---------------------------------------------------------------------------
__global__ __launch_bounds__(256) void gemm_proj(
    const short* __restrict__ A /*wpt[768][768]*/,
    const short* __restrict__ B /*ao [4096][768]*/,
    const float* __restrict__ bias, float* __restrict__ out)
{
    __shared__ short As[8192];
    __shared__ short Bs[8192];
    const int t = threadIdx.x;
    const int lane = t & 63, wid = t >> 6;
    const int quad = lane >> 4, l16 = lane & 15;
    const int wA = wid >> 1, wB = wid & 1;
    const int n0 = blockIdx.x * 128;
    const int m0 = blockIdx.y * 128;

    const int srow = wid * 16 + (lane >> 2), schunk = (lane & 3) * 8;
    const short* ag0 = A + (size_t)(n0 + srow) * CDIM + schunk;
    const short* ag1 = ag0 + (size_t)64 * CDIM;
    const short* bg0 = B + (size_t)(m0 + srow) * CDIM + schunk;
    const short* bg1 = bg0 + (size_t)64 * CDIM;

    f32x4 acc[4][4] = {};
    GEMM_LOOP();

    #pragma unroll
    for (int i = 0; i < 4; ++i) {
        int col0 = n0 + wA*64 + i*16 + quad*4;
        float4 bias4 = *(const float4*)&bias[col0];
        #pragma unroll
        for (int j = 0; j < 4; ++j) {
            int tok = m0 + wB*64 + j*16 + l16;
            float4 o = { acc[i][j][0] + bias4.x, acc[i][j][1] + bias4.y,
                         acc[i][j][2] + bias4.z, acc[i][j][3] + bias4.w };
            *(float4*)(out + (size_t)tok * CDIM + col0) = o;
        }
    }
}

extern "C" void kernel_launch(void* const* d_in, const int* in_sizes, int n_in,
                              void* d_out, int out_size, void* d_ws, size_t ws_size,
                              hipStream_t stream)
{
    const float* x      = (const float*)d_in[0];
    const int*   mask   = (const int*)d_in[1];
    const float* w_qkv  = (const float*)d_in[2];
    const float* w_proj = (const float*)d_in[3];
    const float* b_proj = (const float*)d_in[4];
    float* out = (float*)d_out;

    const size_t SZ = (size_t)NTOK * CDIM;       // 3,145,728
    short* xb  = (short*)d_ws;                   // [4096][768]
    short* wqt = xb  + SZ;                       // [2304][768]
    short* wpt = wqt + (size_t)QKV_COLS * CDIM;  // [768][768]
    short* qb  = wpt + (size_t)CDIM * CDIM;      // [BH][N][64]  (pre-scaled q)
    short* kb  = qb  + SZ;                       // [BH][N][64]
    short* vt  = kb  + SZ;                       // [BH][64][N]
    short* ao  = vt  + SZ;                       // [4096][768]

    dim3 blk(256);
    prep_kernel<<<dim3(5376), blk, 0, stream>>>(x, w_qkv, w_proj, xb, wqt, wpt);
    gemm_qkv<<<dim3(QKV_COLS/128, NTOK/128), blk, 0, stream>>>(wqt, xb, qb, kb, vt);
    attn_kernel<<<dim3(NBLK), blk, 0, stream>>>(qb, kb, vt, mask, ao);
    gemm_proj<<<dim3(CDIM/128, NTOK/128), blk, 0, stream>>>(wpt, ao, b_proj, out);
}